// Round 10
// baseline (6164.968 us; speedup 1.0000x reference)
//
#include <hip/hip_runtime.h>
#include <stdint.h>

#define B_ 128
#define T_ 512
#define D_ 1024
#define H_ 1024

typedef __attribute__((ext_vector_type(8))) short bf16x8;
typedef __attribute__((ext_vector_type(4))) float f32x4;
typedef unsigned int u32;
typedef __attribute__((ext_vector_type(4))) u32 u32x4;

__device__ __forceinline__ ushort f2bf(float f) {
  union { float f; uint32_t u; } v; v.f = f;
  uint32_t u = v.u + 0x7FFFu + ((v.u >> 16) & 1u);
  return (ushort)(u >> 16);
}
__device__ __forceinline__ float bf2f(ushort s) {
  union { uint32_t u; float f; } v; v.u = ((uint32_t)s) << 16;
  return v.f;
}

__device__ __forceinline__ void store_xp(float* p, float v) { *p = v; }
__device__ __forceinline__ void store_xp(ushort* p, float v) { *p = f2bf(v); }

// ---------------- W_hh -> (hi, lo) bf16 split ----------------
__global__ void wsplit_kernel(const float* __restrict__ W,
                              ushort* __restrict__ hi, ushort* __restrict__ lo,
                              int n) {
  int i = blockIdx.x * blockDim.x + threadIdx.x;
  if (i < n) {
    float w = W[i];
    ushort h = f2bf(w);
    hi[i] = h;
    lo[i] = f2bf(w - bf2f(h));
  }
}

// ---------------- zero workspace region ----------------
__global__ void hzero_kernel(uint4* __restrict__ p, int n4) {
  int i = blockIdx.x * blockDim.x + threadIdx.x;
  if (i < n4) p[i] = make_uint4(0, 0, 0, 0);
}

// ---------------- xp = x @ W_ih^T + b_ih + b_hh, stored [T,B,H] ----------------
template <typename XPT>
__global__ __launch_bounds__(256) void xp_gemm(
    const float* __restrict__ x, const float* __restrict__ Wih,
    const float* __restrict__ bih, const float* __restrict__ bhh,
    XPT* __restrict__ xp) {
  __shared__ __align__(16) ushort As[128][40];
  __shared__ __align__(16) ushort Bs[128][40];
  const int tid = threadIdx.x;
  const int lane = tid & 63;
  const int w = tid >> 6;
  const int wm = w >> 1, wn = w & 1;
  const int bm = blockIdx.x;  // 512 M-tiles
  const int bn = blockIdx.y;  // 8 N-tiles

  f32x4 acc[4][4] = {};

  for (int kt = 0; kt < D_ / 32; ++kt) {
    __syncthreads();
#pragma unroll
    for (int i = 0; i < 4; ++i) {
      int c = tid + i * 256;      // 0..1023
      int isB = c >> 9;           // 0: A chunk, 1: B chunk
      int cc = c & 511;
      int row = cc >> 2;          // 0..127
      int col8 = (cc & 3) << 3;   // 0,8,16,24
      const float* src = isB
          ? (Wih + (size_t)(bn * 128 + row) * D_ + kt * 32 + col8)
          : (x + (size_t)(bm * 128 + row) * D_ + kt * 32 + col8);
      float4 f0 = *(const float4*)(src);
      float4 f1 = *(const float4*)(src + 4);
      uint32_t p0 = (uint32_t)f2bf(f0.x) | ((uint32_t)f2bf(f0.y) << 16);
      uint32_t p1 = (uint32_t)f2bf(f0.z) | ((uint32_t)f2bf(f0.w) << 16);
      uint32_t p2 = (uint32_t)f2bf(f1.x) | ((uint32_t)f2bf(f1.y) << 16);
      uint32_t p3 = (uint32_t)f2bf(f1.z) | ((uint32_t)f2bf(f1.w) << 16);
      uint4 pk = make_uint4(p0, p1, p2, p3);
      ushort* dst = isB ? &Bs[row][col8] : &As[row][col8];
      *(uint4*)dst = pk;
    }
    __syncthreads();

    bf16x8 af[4], bfr[4];
#pragma unroll
    for (int fm = 0; fm < 4; ++fm)
      af[fm] = *(const bf16x8*)&As[wm * 64 + fm * 16 + (lane & 15)][(lane >> 4) * 8];
#pragma unroll
    for (int fn = 0; fn < 4; ++fn)
      bfr[fn] = *(const bf16x8*)&Bs[wn * 64 + fn * 16 + (lane & 15)][(lane >> 4) * 8];
#pragma unroll
    for (int fm = 0; fm < 4; ++fm)
#pragma unroll
      for (int fn = 0; fn < 4; ++fn)
        acc[fm][fn] = __builtin_amdgcn_mfma_f32_16x16x32_bf16(
            af[fm], bfr[fn], acc[fm][fn], 0, 0, 0);
  }

  float bias[4];
#pragma unroll
  for (int fn = 0; fn < 4; ++fn) {
    int j = bn * 128 + wn * 64 + fn * 16 + (lane & 15);
    bias[fn] = bih[j] + bhh[j];
  }
#pragma unroll
  for (int fm = 0; fm < 4; ++fm) {
#pragma unroll
    for (int r = 0; r < 4; ++r) {
      int m = bm * 128 + wm * 64 + fm * 16 + ((lane >> 4) * 4) + r;
      int t = m & (T_ - 1);
      int b = m >> 9;  // m / T_
      size_t base = (size_t)t * (B_ * H_) + (size_t)b * H_;
#pragma unroll
      for (int fn = 0; fn < 4; ++fn) {
        int j = bn * 128 + wn * 64 + fn * 16 + (lane & 15);
        store_xp(xp + base + j, acc[fm][fn][r] + bias[fn]);
      }
    }
  }
}

// ---------------- persistent recurrence v8: 4-chain rotation ----------------
// 64 WGs: grp = bid>>5 (0..1) serves replicas rep0..rep0+3 (rep0=grp*4);
// wgc = bid&31 = col slice. Phases p: chain c=p&3, step t=p>>2. Per phase:
//  1. poll (cn,tn) — posts happened 3 phases (~7us) earlier -> first-try hit
//  2. issue 18-load gather (cn,tn) into g regs (sc0 sc1, coalesced)
//  3. compute (c,t) from LDS stage[p&1] (gather flies over this)
//  4. vmcnt(0) (landed gather free + h-store ack) -> post c
//  5. stage g -> stage[(p+1)&1] (own-wave region, no barrier)
// Only vmcnt(0) drains (robust vs compiler VMEM). One g group live (no spills).
// Safety: H-write for step t gated by poll(c,t) => all 32 producers finished
// step t-1 incl. their H reads (round-8 invariant).
template <typename XPT>
__global__ __launch_bounds__(256, 1) void rnn_persist(
    const ushort* __restrict__ Whi, const ushort* __restrict__ Wlo,
    const XPT* __restrict__ xp,
    u32* __restrict__ hpk,   // [2][B_][H_] packed bf16 hi|lo
    u32* __restrict__ cnt,   // [256][16]: line (rep*32+wgc), slot kq
    float* __restrict__ out) {
  __shared__ __align__(16) u32 stage[2][4 * 16 * 256];   // 128 KB
  __shared__ __align__(16) f32x4 red[2][4][2][64];       // 16 KB

  const int bid = blockIdx.x;
  const int grp = bid >> 5;   // 0..1
  const int wgc = bid & 31;   // cols [wgc*32, wgc*32+32)
  const int tid = threadIdx.x;
  const int lane = tid & 63;
  const int kq = tid >> 6;    // wave = K-quarter
  const int r16 = lane & 15;
  const int kg = lane >> 4;   // 0..3
  const int nf_e = kq & 1;
  const int rh_e = kq >> 1;
  const int l5 = lane & 31;

  // ---- W fragments in registers (shared by all 4 chains; same cols) ----
  bf16x8 wbh[8][2], wbl[8][2];
#pragma unroll
  for (int ks = 0; ks < 8; ++ks) {
#pragma unroll
    for (int nf = 0; nf < 2; ++nf) {
      int col = wgc * 32 + nf * 16 + r16;
      int k = kq * 256 + ks * 32 + kg * 8;
      wbh[ks][nf] = *(const bf16x8*)(Whi + (size_t)col * H_ + k);
      wbl[ks][nf] = *(const bf16x8*)(Wlo + (size_t)col * H_ + k);
    }
  }

  const int rep0 = grp * 4;                             // chain c -> rep0+c
  const int ecol = wgc * 32 + nf_e * 16 + r16;
  const int erow_base = rep0 * 16 + kg * 4 + rh_e * 2;  // + c*16
  u32* post_base = cnt + (size_t)(rep0 * 32 + wgc) * 16 + kq;                 // + c*512
  const u32* poll_base = cnt + (size_t)(rep0 * 32 + kq * 8 + (l5 >> 2)) * 16
                       + (l5 & 3);                                            // + c*512
  const int sbase = kq * (16 * 256);
  const int swz_rd = (r16 & 7) << 2;

  u32x4 g[16];
  u32 xpN[2], xpC[2];

  // helper: issue 2 xp + 16 gather loads for (chain cc, step tt)
  auto issue = [&](int cc, int tt) {
#pragma unroll
    for (int e = 0; e < 2; ++e) {
      const XPT* a = xp + (size_t)tt * (B_ * H_)
                   + (size_t)(erow_base + cc * 16 + e) * H_ + ecol;
      if constexpr (sizeof(XPT) == 4)
        asm volatile("global_load_dword %0, %1, off" : "=&v"(xpN[e]) : "v"(a) : "memory");
      else
        asm volatile("global_load_ushort %0, %1, off" : "=&v"(xpN[e]) : "v"(a) : "memory");
    }
    const u32* gb = hpk + (size_t)(tt & 1) * (B_ * H_)
                  + (size_t)(rep0 + cc) * 16 * H_ + kq * 256 + lane * 4;
#pragma unroll
    for (int i = 0; i < 16; ++i) {
      const u32* a = gb + (size_t)i * H_;
      asm volatile("global_load_dwordx4 %0, %1, off sc0 sc1"
                   : "=&v"(g[i]) : "v"(a) : "memory");
    }
  };

  // ---- prologue: gather (chain 0, step 0), drain, stage into stage[0] ----
  issue(0, 0);
  asm volatile("s_waitcnt vmcnt(0)" ::: "memory");
  __builtin_amdgcn_sched_barrier(0);
#pragma unroll
  for (int i = 0; i < 16; ++i) {
    int idx = sbase + i * 256 + ((lane * 4) ^ ((i & 7) << 2));
    *(u32x4*)&stage[0][idx] = g[i];
  }
  xpC[0] = xpN[0]; xpC[1] = xpN[1];

  for (int p = 0; p < 4 * T_; ++p) {
    const int c = p & 3, t = p >> 2;
    const int cn = (p + 1) & 3, tn = (p + 1) >> 2;
    const int su = p & 1;

    // 1. poll (cn, tn): producers posted 3 phases ago -> first-try hit
    if (tn > 0 && tn < T_) {
      const u32* pp = poll_base + (size_t)cn * 512;
      const u32 tgt = (u32)tn;
      for (;;) {
        u32 v = __hip_atomic_load(pp, __ATOMIC_RELAXED, __HIP_MEMORY_SCOPE_AGENT);
        if (__all((int)(v >= tgt))) break;
        __builtin_amdgcn_s_sleep(1);
      }
    }
    // 2. issue gather for (cn, tn) — flies over step 3's compute
    if (tn < T_) issue(cn, tn);

    // 3. compute (c, t) from stage[su]
    f32x4 acc[2] = {};
    {
      const u32* st = &stage[su][0];
      const int rbase = sbase + r16 * 256;
#pragma unroll
      for (int ks = 0; ks < 8; ++ks) {
        int colq = ks * 32 + kg * 8;
        u32x4 d0 = *(const u32x4*)&st[rbase + ((colq) ^ swz_rd)];
        u32x4 d1 = *(const u32x4*)&st[rbase + ((colq + 4) ^ swz_rd)];
        union { u32 u[4]; bf16x8 v; } ah, al;
        ah.u[0] = __builtin_amdgcn_perm(d0[1], d0[0], 0x05040100u);
        ah.u[1] = __builtin_amdgcn_perm(d0[3], d0[2], 0x05040100u);
        ah.u[2] = __builtin_amdgcn_perm(d1[1], d1[0], 0x05040100u);
        ah.u[3] = __builtin_amdgcn_perm(d1[3], d1[2], 0x05040100u);
        al.u[0] = __builtin_amdgcn_perm(d0[1], d0[0], 0x07060302u);
        al.u[1] = __builtin_amdgcn_perm(d0[3], d0[2], 0x07060302u);
        al.u[2] = __builtin_amdgcn_perm(d1[1], d1[0], 0x07060302u);
        al.u[3] = __builtin_amdgcn_perm(d1[3], d1[2], 0x07060302u);
#pragma unroll
        for (int nf = 0; nf < 2; ++nf) {
          acc[nf] = __builtin_amdgcn_mfma_f32_16x16x32_bf16(ah.v, wbh[ks][nf], acc[nf], 0, 0, 0);
          acc[nf] = __builtin_amdgcn_mfma_f32_16x16x32_bf16(al.v, wbh[ks][nf], acc[nf], 0, 0, 0);
          acc[nf] = __builtin_amdgcn_mfma_f32_16x16x32_bf16(ah.v, wbl[ks][nf], acc[nf], 0, 0, 0);
        }
      }
    }
    red[su][kq][0][lane] = acc[0];
    red[su][kq][1][lane] = acc[1];
    __syncthreads();
    {
      f32x4 sum = red[su][0][nf_e][lane];
      sum += red[su][1][nf_e][lane];
      sum += red[su][2][nf_e][lane];
      sum += red[su][3][nf_e][lane];
      float s0 = rh_e ? sum[2] : sum[0];
      float s1 = rh_e ? sum[3] : sum[1];
      float xv0, xv1;
      if constexpr (sizeof(XPT) == 4) {
        union { u32 u; float f; } c0, c1; c0.u = xpC[0]; c1.u = xpC[1];
        xv0 = c0.f; xv1 = c1.f;
      } else {
        xv0 = bf2f((ushort)xpC[0]); xv1 = bf2f((ushort)xpC[1]);
      }
      float h0 = tanhf(s0 + xv0);
      float h1 = tanhf(s1 + xv1);
      ushort hb0 = f2bf(h0), hb1 = f2bf(h1);
      u32 pk0 = (u32)hb0 | ((u32)f2bf(h0 - bf2f(hb0)) << 16);
      u32 pk1 = (u32)hb1 | ((u32)f2bf(h1 - bf2f(hb1)) << 16);
      const int erow0 = erow_base + c * 16;
      u32* Hn = hpk + (size_t)((t + 1) & 1) * (B_ * H_);
      __hip_atomic_store(Hn + (size_t)erow0 * H_ + ecol, pk0,
                         __ATOMIC_RELAXED, __HIP_MEMORY_SCOPE_AGENT);
      __hip_atomic_store(Hn + (size_t)(erow0 + 1) * H_ + ecol, pk1,
                         __ATOMIC_RELAXED, __HIP_MEMORY_SCOPE_AGENT);
      if (t == T_ - 1) {
        out[(size_t)erow0 * H_ + ecol] = h0;
        out[(size_t)(erow0 + 1) * H_ + ecol] = h1;
      }
    }

    // 4. single drain: gather landed during compute (free) + h-store ack
    asm volatile("s_waitcnt vmcnt(0)" ::: "memory");
    __builtin_amdgcn_sched_barrier(0);
    // 5. post chain c: step t complete
    if (lane == 0)
      __hip_atomic_store(post_base + (size_t)c * 512, (u32)(t + 1),
                         __ATOMIC_RELAXED, __HIP_MEMORY_SCOPE_AGENT);
    // 6. stage gathered (cn, tn) into the other LDS buffer
    if (tn < T_) {
#pragma unroll
      for (int i = 0; i < 16; ++i) {
        int idx = sbase + i * 256 + ((lane * 4) ^ ((i & 7) << 2));
        *(u32x4*)&stage[su ^ 1][idx] = g[i];
      }
      xpC[0] = xpN[0]; xpC[1] = xpN[1];
    }
  }
}

// ---------------- launch ----------------
extern "C" void kernel_launch(void* const* d_in, const int* in_sizes, int n_in,
                              void* d_out, int out_size, void* d_ws, size_t ws_size,
                              hipStream_t stream) {
  const float* x    = (const float*)d_in[0];
  const float* W_ih = (const float*)d_in[1];
  const float* W_hh = (const float*)d_in[2];
  const float* b_ih = (const float*)d_in[3];
  const float* b_hh = (const float*)d_in[4];
  float* out = (float*)d_out;

  const size_t xp_f32_bytes = (size_t)T_ * B_ * H_ * 4;   // 256 MB
  const size_t xp_bf_bytes  = xp_f32_bytes / 2;           // 128 MB
  const size_t wsp_bytes    = 2 * (size_t)H_ * H_ * 2;    // 4 MB (hi+lo)
  const size_t hpk_bytes    = 2 * (size_t)B_ * H_ * 4;    // 1 MB packed dbuf
  const size_t cnt_bytes    = 256 * 64;                   // 16 KB

  bool fp32xp = ws_size >= xp_f32_bytes + wsp_bytes + hpk_bytes + cnt_bytes;
  bool bf16xp = !fp32xp && ws_size >= xp_bf_bytes + wsp_bytes + hpk_bytes + cnt_bytes;
  if (!fp32xp && !bf16xp) return;

  char* p = (char*)d_ws;
  size_t xp_bytes = fp32xp ? xp_f32_bytes : xp_bf_bytes;
  char* xp_raw = p;                       p += xp_bytes;
  ushort* Whi = (ushort*)p;               p += (size_t)H_ * H_ * 2;
  ushort* Wlo = (ushort*)p;               p += (size_t)H_ * H_ * 2;
  u32* hpk = (u32*)p;                     p += hpk_bytes;
  u32* cnt = (u32*)p;

  // 1) split W_hh
  {
    int n = H_ * H_;
    wsplit_kernel<<<(n + 255) / 256, 256, 0, stream>>>(W_hh, Whi, Wlo, n);
  }
  // 2) zero hpk + counters (contiguous; re-done every launch)
  {
    int n4 = (int)((hpk_bytes + cnt_bytes) / 16);
    hzero_kernel<<<(n4 + 255) / 256, 256, 0, stream>>>((uint4*)hpk, n4);
  }
  // 3) xp GEMM
  dim3 gxp(512, 8);
  if (fp32xp)
    xp_gemm<float><<<gxp, 256, 0, stream>>>(x, W_ih, b_ih, b_hh, (float*)xp_raw);
  else
    xp_gemm<ushort><<<gxp, 256, 0, stream>>>(x, W_ih, b_ih, b_hh, (ushort*)xp_raw);

  // 4) persistent recurrence: 64 WGs, 4 chains per WG
  if (fp32xp)
    rnn_persist<float><<<64, 256, 0, stream>>>(Whi, Wlo, (const float*)xp_raw,
                                               hpk, cnt, out);
  else
    rnn_persist<ushort><<<64, 256, 0, stream>>>(Whi, Wlo, (const ushort*)xp_raw,
                                                hpk, cnt, out);
}

// Round 11
// 2086.681 us; speedup vs baseline: 2.9544x; 2.9544x over previous
//
#include <hip/hip_runtime.h>
#include <stdint.h>

#define B_ 128
#define T_ 512
#define D_ 1024
#define H_ 1024

typedef __attribute__((ext_vector_type(8))) short bf16x8;
typedef __attribute__((ext_vector_type(4))) float f32x4;
typedef unsigned int u32;
typedef __attribute__((ext_vector_type(4))) u32 u32x4;

__device__ __forceinline__ ushort f2bf(float f) {
  union { float f; uint32_t u; } v; v.f = f;
  uint32_t u = v.u + 0x7FFFu + ((v.u >> 16) & 1u);
  return (ushort)(u >> 16);
}
__device__ __forceinline__ float bf2f(ushort s) {
  union { uint32_t u; float f; } v; v.u = ((uint32_t)s) << 16;
  return v.f;
}

__device__ __forceinline__ void store_xp(float* p, float v) { *p = v; }
__device__ __forceinline__ void store_xp(ushort* p, float v) { *p = f2bf(v); }
__device__ __forceinline__ float load_xp(const float* p) { return *p; }
__device__ __forceinline__ float load_xp(const ushort* p) { return bf2f(*p); }

// ---------------- W_hh -> (hi, lo) bf16 split ----------------
__global__ void wsplit_kernel(const float* __restrict__ W,
                              ushort* __restrict__ hi, ushort* __restrict__ lo,
                              int n) {
  int i = blockIdx.x * blockDim.x + threadIdx.x;
  if (i < n) {
    float w = W[i];
    ushort h = f2bf(w);
    hi[i] = h;
    lo[i] = f2bf(w - bf2f(h));
  }
}

// ---------------- zero workspace region ----------------
__global__ void hzero_kernel(uint4* __restrict__ p, int n4) {
  int i = blockIdx.x * blockDim.x + threadIdx.x;
  if (i < n4) p[i] = make_uint4(0, 0, 0, 0);
}

// ---------------- xp = x @ W_ih^T + b_ih + b_hh, stored [T,B,H] ----------------
// GRID TRANSPOSED vs round 8: (8, 512), bn = blockIdx.x (fastest) so the 8
// N-tiles of one M-band are co-resident -> x streamed from HBM ~once (was 8x).
template <typename XPT>
__global__ __launch_bounds__(256) void xp_gemm(
    const float* __restrict__ x, const float* __restrict__ Wih,
    const float* __restrict__ bih, const float* __restrict__ bhh,
    XPT* __restrict__ xp) {
  __shared__ __align__(16) ushort As[128][40];
  __shared__ __align__(16) ushort Bs[128][40];
  const int tid = threadIdx.x;
  const int lane = tid & 63;
  const int w = tid >> 6;
  const int wm = w >> 1, wn = w & 1;
  const int bn = blockIdx.x;  // 8 N-tiles (fastest -> L2 reuse of x)
  const int bm = blockIdx.y;  // 512 M-tiles

  f32x4 acc[4][4] = {};

  for (int kt = 0; kt < D_ / 32; ++kt) {
    __syncthreads();
#pragma unroll
    for (int i = 0; i < 4; ++i) {
      int c = tid + i * 256;      // 0..1023
      int isB = c >> 9;           // 0: A chunk, 1: B chunk
      int cc = c & 511;
      int row = cc >> 2;          // 0..127
      int col8 = (cc & 3) << 3;   // 0,8,16,24
      const float* src = isB
          ? (Wih + (size_t)(bn * 128 + row) * D_ + kt * 32 + col8)
          : (x + (size_t)(bm * 128 + row) * D_ + kt * 32 + col8);
      float4 f0 = *(const float4*)(src);
      float4 f1 = *(const float4*)(src + 4);
      uint32_t p0 = (uint32_t)f2bf(f0.x) | ((uint32_t)f2bf(f0.y) << 16);
      uint32_t p1 = (uint32_t)f2bf(f0.z) | ((uint32_t)f2bf(f0.w) << 16);
      uint32_t p2 = (uint32_t)f2bf(f1.x) | ((uint32_t)f2bf(f1.y) << 16);
      uint32_t p3 = (uint32_t)f2bf(f1.z) | ((uint32_t)f2bf(f1.w) << 16);
      uint4 pk = make_uint4(p0, p1, p2, p3);
      ushort* dst = isB ? &Bs[row][col8] : &As[row][col8];
      *(uint4*)dst = pk;
    }
    __syncthreads();

    bf16x8 af[4], bfr[4];
#pragma unroll
    for (int fm = 0; fm < 4; ++fm)
      af[fm] = *(const bf16x8*)&As[wm * 64 + fm * 16 + (lane & 15)][(lane >> 4) * 8];
#pragma unroll
    for (int fn = 0; fn < 4; ++fn)
      bfr[fn] = *(const bf16x8*)&Bs[wn * 64 + fn * 16 + (lane & 15)][(lane >> 4) * 8];
#pragma unroll
    for (int fm = 0; fm < 4; ++fm)
#pragma unroll
      for (int fn = 0; fn < 4; ++fn)
        acc[fm][fn] = __builtin_amdgcn_mfma_f32_16x16x32_bf16(
            af[fm], bfr[fn], acc[fm][fn], 0, 0, 0);
  }

  float bias[4];
#pragma unroll
  for (int fn = 0; fn < 4; ++fn) {
    int j = bn * 128 + wn * 64 + fn * 16 + (lane & 15);
    bias[fn] = bih[j] + bhh[j];
  }
#pragma unroll
  for (int fm = 0; fm < 4; ++fm) {
#pragma unroll
    for (int r = 0; r < 4; ++r) {
      int m = bm * 128 + wm * 64 + fm * 16 + ((lane >> 4) * 4) + r;
      int t = m & (T_ - 1);
      int b = m >> 9;  // m / T_
      size_t base = (size_t)t * (B_ * H_) + (size_t)b * H_;
#pragma unroll
      for (int fn = 0; fn < 4; ++fn) {
        int j = bn * 128 + wn * 64 + fn * 16 + (lane & 15);
        store_xp(xp + base + j, acc[fm][fn][r] + bias[fn]);
      }
    }
  }
}

// ---------------- persistent recurrence v9: round-8 + per-wave-slot posts ----------------
// 256 WGs: replica = bid&7 (16 batches), wgc = bid>>3 (32 cols). Wave = K-quarter.
// Per-wave producer poll (8 WGs x 4 slots via 32 lanes); posts are plain relaxed
// agent STORES (value t+1 into slot kq of own WG line) - no RMW serialization.
// WAR invariant: union of the 4 waves' poll sets = all 128 wave-posts of the
// replica checked >= t before __syncthreads -> h-buffer write safe (round-8 proof).
template <typename XPT>
__global__ __launch_bounds__(256, 1) void rnn_persist(
    const ushort* __restrict__ Whi, const ushort* __restrict__ Wlo,
    const XPT* __restrict__ xp,
    u32* __restrict__ hpk,   // [2][B_][H_] packed bf16 hi|lo
    u32* __restrict__ cnt,   // [256][16]: line (rep*32+wgc), slots 0..3 = waves
    float* __restrict__ out) {
  __shared__ __align__(16) u32 stage[4 * 16 * 256];      // 64 KB
  __shared__ __align__(16) f32x4 red[2][4][2][64];       // 16 KB

  const int bid = blockIdx.x;
  const int rep = bid & 7;    // batches [rep*16, rep*16+16)
  const int wgc = bid >> 3;   // cols [wgc*32, wgc*32+32)
  const int tid = threadIdx.x;
  const int lane = tid & 63;
  const int kq = tid >> 6;    // wave = K-quarter
  const int r16 = lane & 15;
  const int kg = lane >> 4;   // 0..3
  const int nf_e = kq & 1;    // epilogue: nf slice
  const int rh_e = kq >> 1;   // epilogue: row pair
  const int l5 = lane & 31;

  // ---- preload W fragments into registers (128 VGPR) ----
  bf16x8 wbh[8][2], wbl[8][2];
#pragma unroll
  for (int ks = 0; ks < 8; ++ks) {
#pragma unroll
    for (int nf = 0; nf < 2; ++nf) {
      int col = wgc * 32 + nf * 16 + r16;
      int k = kq * 256 + ks * 32 + kg * 8;
      wbh[ks][nf] = *(const bf16x8*)(Whi + (size_t)col * H_ + k);
      wbl[ks][nf] = *(const bf16x8*)(Wlo + (size_t)col * H_ + k);
    }
  }

  const int erow0 = rep * 16 + kg * 4 + rh_e * 2;
  const int ecol = wgc * 32 + nf_e * 16 + r16;
  // own post slot: line (rep*32+wgc), slot kq
  u32* mypost = cnt + (size_t)(rep * 32 + wgc) * 16 + kq;
  // poll: wave kq's 8 producer WGs (rep, kq*8 + 0..7) x 4 slots -> 32 lanes
  const u32* mypoll = cnt + (size_t)(rep * 32 + kq * 8 + (l5 >> 2)) * 16 + (l5 & 3);
  const int sbase = kq * (16 * 256);

  for (int t = 0; t < T_; ++t) {
    const u32* Hq = hpk + (size_t)(t & 1) * (B_ * H_);
    u32* Hn = hpk + (size_t)((t + 1) & 1) * (B_ * H_);

    // ---- per-wave poll: all 4 waves of my 8 producers posted >= t ----
    if (t) {
      const u32 target = (u32)t;
      for (;;) {
        u32 v = __hip_atomic_load(mypoll, __ATOMIC_RELAXED, __HIP_MEMORY_SCOPE_AGENT);
        if (__all((int)(v >= target))) break;
        __builtin_amdgcn_s_sleep(1);
      }
    }

    // xp prefetch (issued first -> oldest in vmcnt order)
    float xpv[2];
#pragma unroll
    for (int e = 0; e < 2; ++e)
      xpv[e] = load_xp(xp + (size_t)t * (B_ * H_) + (size_t)(erow0 + e) * H_ + ecol);

    // ---- coalesced gather: wave kq pulls its 16-row x 256-col u32 quarter ----
    u32x4 g[16];
    {
      const u32* gb = Hq + (size_t)rep * 16 * H_ + kq * 256 + lane * 4;
#pragma unroll
      for (int i = 0; i < 16; ++i) {
        const u32* a = gb + (size_t)i * H_;
        asm volatile("global_load_dwordx4 %0, %1, off sc0 sc1"
                     : "=&v"(g[i]) : "v"(a) : "memory");
      }
    }
    // chunked drain: xp(2) + 16 gathers outstanding; vmcnt(8) = oldest 10 done
    asm volatile("s_waitcnt vmcnt(8)" ::: "memory");
    __builtin_amdgcn_sched_barrier(0);
#pragma unroll
    for (int i = 0; i < 8; ++i) {
      int idx = sbase + i * 256 + ((lane * 4) ^ ((i & 7) << 2));
      *(u32x4*)&stage[idx] = g[i];
    }
    asm volatile("s_waitcnt vmcnt(0)" ::: "memory");
    __builtin_amdgcn_sched_barrier(0);
#pragma unroll
    for (int i = 8; i < 16; ++i) {
      int idx = sbase + i * 256 + ((lane * 4) ^ ((i & 7) << 2));
      *(u32x4*)&stage[idx] = g[i];
    }

    // ---- A-frags from LDS + MFMA (DS in-order per wave; no barrier) ----
    f32x4 acc[2] = {};
    const int rbase = sbase + r16 * 256;
    const int s = (r16 & 7) << 2;
#pragma unroll
    for (int ks = 0; ks < 8; ++ks) {
      int colq = ks * 32 + kg * 8;
      u32x4 d0 = *(const u32x4*)&stage[rbase + ((colq) ^ s)];
      u32x4 d1 = *(const u32x4*)&stage[rbase + ((colq + 4) ^ s)];
      union { u32 u[4]; bf16x8 v; } ah, al;
      ah.u[0] = __builtin_amdgcn_perm(d0[1], d0[0], 0x05040100u);
      ah.u[1] = __builtin_amdgcn_perm(d0[3], d0[2], 0x05040100u);
      ah.u[2] = __builtin_amdgcn_perm(d1[1], d1[0], 0x05040100u);
      ah.u[3] = __builtin_amdgcn_perm(d1[3], d1[2], 0x05040100u);
      al.u[0] = __builtin_amdgcn_perm(d0[1], d0[0], 0x07060302u);
      al.u[1] = __builtin_amdgcn_perm(d0[3], d0[2], 0x07060302u);
      al.u[2] = __builtin_amdgcn_perm(d1[1], d1[0], 0x07060302u);
      al.u[3] = __builtin_amdgcn_perm(d1[3], d1[2], 0x07060302u);
#pragma unroll
      for (int nf = 0; nf < 2; ++nf) {
        acc[nf] = __builtin_amdgcn_mfma_f32_16x16x32_bf16(ah.v, wbh[ks][nf], acc[nf], 0, 0, 0);
        acc[nf] = __builtin_amdgcn_mfma_f32_16x16x32_bf16(al.v, wbh[ks][nf], acc[nf], 0, 0, 0);
        acc[nf] = __builtin_amdgcn_mfma_f32_16x16x32_bf16(ah.v, wbl[ks][nf], acc[nf], 0, 0, 0);
      }
    }

    // ---- all-to-all K reduce (parity double-buffered, one barrier) ----
    const int par = t & 1;
    red[par][kq][0][lane] = acc[0];
    red[par][kq][1][lane] = acc[1];
    __syncthreads();   // joins all 4 waves => all 32 producers done (safety)

    // ---- parallel epilogue: vector red reads + uniform select ----
    {
      f32x4 sum = red[par][0][nf_e][lane];
      sum += red[par][1][nf_e][lane];
      sum += red[par][2][nf_e][lane];
      sum += red[par][3][nf_e][lane];
      float s0 = rh_e ? sum[2] : sum[0];
      float s1 = rh_e ? sum[3] : sum[1];
      float h0 = tanhf(s0 + xpv[0]);
      float h1 = tanhf(s1 + xpv[1]);
      ushort hb0 = f2bf(h0), hb1 = f2bf(h1);
      u32 pk0 = (u32)hb0 | ((u32)f2bf(h0 - bf2f(hb0)) << 16);
      u32 pk1 = (u32)hb1 | ((u32)f2bf(h1 - bf2f(hb1)) << 16);
      __hip_atomic_store(Hn + (size_t)erow0 * H_ + ecol, pk0,
                         __ATOMIC_RELAXED, __HIP_MEMORY_SCOPE_AGENT);
      __hip_atomic_store(Hn + (size_t)(erow0 + 1) * H_ + ecol, pk1,
                         __ATOMIC_RELAXED, __HIP_MEMORY_SCOPE_AGENT);
      if (t == T_ - 1) {
        out[(size_t)erow0 * H_ + ecol] = h0;
        out[(size_t)(erow0 + 1) * H_ + ecol] = h1;
      }
    }

    // ---- completion: drain stores, post own wave slot (plain store) ----
    asm volatile("s_waitcnt vmcnt(0)" ::: "memory");
    __builtin_amdgcn_sched_barrier(0);
    if (lane == 0)
      __hip_atomic_store(mypost, (u32)(t + 1),
                         __ATOMIC_RELAXED, __HIP_MEMORY_SCOPE_AGENT);
  }
}

// ---------------- launch ----------------
extern "C" void kernel_launch(void* const* d_in, const int* in_sizes, int n_in,
                              void* d_out, int out_size, void* d_ws, size_t ws_size,
                              hipStream_t stream) {
  const float* x    = (const float*)d_in[0];
  const float* W_ih = (const float*)d_in[1];
  const float* W_hh = (const float*)d_in[2];
  const float* b_ih = (const float*)d_in[3];
  const float* b_hh = (const float*)d_in[4];
  float* out = (float*)d_out;

  const size_t xp_f32_bytes = (size_t)T_ * B_ * H_ * 4;   // 256 MB
  const size_t xp_bf_bytes  = xp_f32_bytes / 2;           // 128 MB
  const size_t wsp_bytes    = 2 * (size_t)H_ * H_ * 2;    // 4 MB (hi+lo)
  const size_t hpk_bytes    = 2 * (size_t)B_ * H_ * 4;    // 1 MB packed dbuf
  const size_t cnt_bytes    = 256 * 64;                   // 16 KB

  bool fp32xp = ws_size >= xp_f32_bytes + wsp_bytes + hpk_bytes + cnt_bytes;
  bool bf16xp = !fp32xp && ws_size >= xp_bf_bytes + wsp_bytes + hpk_bytes + cnt_bytes;
  if (!fp32xp && !bf16xp) return;

  char* p = (char*)d_ws;
  size_t xp_bytes = fp32xp ? xp_f32_bytes : xp_bf_bytes;
  char* xp_raw = p;                       p += xp_bytes;
  ushort* Whi = (ushort*)p;               p += (size_t)H_ * H_ * 2;
  ushort* Wlo = (ushort*)p;               p += (size_t)H_ * H_ * 2;
  u32* hpk = (u32*)p;                     p += hpk_bytes;
  u32* cnt = (u32*)p;

  // 1) split W_hh
  {
    int n = H_ * H_;
    wsplit_kernel<<<(n + 255) / 256, 256, 0, stream>>>(W_hh, Whi, Wlo, n);
  }
  // 2) zero hpk + counters (contiguous; re-done every launch)
  {
    int n4 = (int)((hpk_bytes + cnt_bytes) / 16);
    hzero_kernel<<<(n4 + 255) / 256, 256, 0, stream>>>((uint4*)hpk, n4);
  }
  // 3) xp GEMM — transposed grid: bn fastest so x is read from HBM ~once
  dim3 gxp(8, 512);
  if (fp32xp)
    xp_gemm<float><<<gxp, 256, 0, stream>>>(x, W_ih, b_ih, b_hh, (float*)xp_raw);
  else
    xp_gemm<ushort><<<gxp, 256, 0, stream>>>(x, W_ih, b_ih, b_hh, (ushort*)xp_raw);

  // 4) persistent recurrence (256 WGs, 1 WG/CU)
  if (fp32xp)
    rnn_persist<float><<<256, 256, 0, stream>>>(Whi, Wlo, (const float*)xp_raw,
                                                hpk, cnt, out);
  else
    rnn_persist<ushort><<<256, 256, 0, stream>>>(Whi, Wlo, (const ushort*)xp_raw,
                                                 hpk, cnt, out);
}